// Round 4
// baseline (346.106 us; speedup 1.0000x reference)
//
#include <hip/hip_runtime.h>
#include <hip/hip_bf16.h>
#include <math.h>

#define B 128
#define L 196
#define K 512
#define NCLS 15
#define NT 32
#define NTILES 7

// d_out layout (floats)
#define DIFF_OFF 12845056
#define ID_OFF   12845057
#define OT_OFF   12945409

// ws layout (float indices)
#define WS_N2   0                    // 75*512 ([0..14]=top, 15+j*15+c = lvl)
#define WS_INVE 38400                // 15*512
#define WS_CBT  46080                // fp32 transposed codebooks [col][d]
#define CBT_LVL 491520               // float offset of lvl mats inside CBT
#define WS_EBT_BYTES ((size_t)(46080 + 4469760) * 4)  // bf16 [col][k] codebooks
#define EBT_LVL_BYTES 983040         // byte offset of lvl mats inside EBT

#define BAND 2.5f
#define CCAP 512

typedef __attribute__((ext_vector_type(8))) short s16x8;
typedef __attribute__((ext_vector_type(4))) float f32x4;
typedef __attribute__((ext_vector_type(4))) unsigned short u16x4;

__device__ inline unsigned short f2bf(float f) {
    __hip_bfloat16 h = __float2bfloat16(f);
    return *reinterpret_cast<unsigned short*>(&h);
}

// ---------------------------------------------------------------------------
// precompute: cbT fp32 [col][d], EBT bf16 [col][k], exact col norms, inve.
// ---------------------------------------------------------------------------
__global__ __launch_bounds__(256) void precompute(
    const float* __restrict__ cb_top, const float* __restrict__ cb_lvl,
    float* __restrict__ ws)
{
    __shared__ float Ld[128][65];
    __shared__ float ps[64][4];
    const int m = blockIdx.x >> 3;
    const int c0 = (blockIdx.x & 7) * 64;
    const bool top = m < NCLS;
    const int D = top ? 64 : 128;
    const float* src = top ? cb_top + (size_t)m * 64 * K
                           : cb_lvl + (size_t)(m - NCLS) * 128 * K;
    float* cbT = ws + WS_CBT + (top ? (size_t)m * K * 64
                                    : (size_t)CBT_LVL + (size_t)(m - NCLS) * K * 128);
    unsigned short* ebt = (unsigned short*)((char*)ws + WS_EBT_BYTES +
        (top ? (size_t)m * K * 64 * 2
             : (size_t)EBT_LVL_BYTES + (size_t)(m - NCLS) * K * 128 * 2));
    const int tid = threadIdx.x;

    for (int e = tid; e < D * 64; e += 256) {
        int d = e >> 6, cc = e & 63;
        Ld[d][cc] = src[(size_t)d * K + c0 + cc];
    }
    __syncthreads();

    const int col = tid >> 2, q = tid & 3;
    const int seg = D >> 2;
    float ss = 0.f;
    for (int i = 0; i < seg; ++i) {
        int d = q * seg + i;
        float v = Ld[d][col];
        ss = fmaf(v, v, ss);
        cbT[(size_t)(c0 + col) * D + d] = v;
        ebt[(size_t)(c0 + col) * D + d] = f2bf(v);
    }
    ps[col][q] = ss;
    __syncthreads();
    if (tid < 64) {
        float n2 = (ps[tid][0] + ps[tid][1]) + (ps[tid][2] + ps[tid][3]);
        ws[WS_N2 + (size_t)m * K + c0 + tid] = n2;
        if (m >= NCLS && m < 2 * NCLS)
            ws[WS_INVE + (size_t)(m - NCLS) * K + c0 + tid] = 1.f / (sqrtf(n2) + 1e-8f);
    }
}

// ---------------------------------------------------------------------------
// Fully fused: per block (tile, b, level j): recompute top-VQ locally (q4 in
// LDS), then level-VQ with exact rescore. One dispatch for everything.
// ---------------------------------------------------------------------------
__global__ __launch_bounds__(256, 6) void vq_all(
    const float* __restrict__ input, const int* __restrict__ label,
    float* __restrict__ ws, float* __restrict__ out)
{
    __shared__ char uA[8192];                   // x4_s (32x72 u16) then q4f (32x64 f32)
    __shared__ unsigned short xL_s[NT * 136];   // level x bf16, stride 136
    __shared__ float clv[CCAP];
    __shared__ unsigned int clist[CCAP];
    __shared__ float wmin_s[4][NT];
    __shared__ float rowMinG[NT];
    __shared__ unsigned long long best_s[NT];
    __shared__ float xn4_s[NT], xnL_s[NT], xnq_s[NT];
    __shared__ float otZ_s[NT], otW_s[NT];
    __shared__ float dacc_s;
    __shared__ int ccnt;

    unsigned short* x4_s = (unsigned short*)uA;
    float* q4f = (float*)uA;

    const int tid = threadIdx.x;
    const int t0 = blockIdx.x * NT;
    const int b = blockIdx.y;
    const int j = blockIdx.z;                   // level 0..3
    const bool OT = (j == 0);
    const bool addTop = (j == 3);
    const int c = label[b];

    const float* xin4 = input + ((size_t)(4 * B + b) * L) * 64;
    const float* xinj = input + ((size_t)(j * B + b) * L) * 64;
    const float* n2T = ws + WS_N2 + (size_t)c * K;
    const float* n2L = ws + WS_N2 + (size_t)(NCLS + j * NCLS + c) * K;
    const float* ive = ws + WS_INVE + (size_t)c * K;
    const float* cbT_T = ws + WS_CBT + (size_t)c * (K * 64);
    const float* cbT_L = ws + WS_CBT + CBT_LVL + (size_t)(j * NCLS + c) * (K * 128);
    const unsigned short* ebT =
        (const unsigned short*)((const char*)ws + WS_EBT_BYTES) + (size_t)c * (K * 64);
    const unsigned short* ebL =
        (const unsigned short*)((const char*)ws + WS_EBT_BYTES + EBT_LVL_BYTES) +
        (size_t)(j * NCLS + c) * (K * 128);

    const int wid = tid >> 6, lane = tid & 63, l15 = lane & 15, l4 = lane >> 4;

    // ---- P0: init ----
    if (tid < NT) {
        xn4_s[tid] = 0.f; xnL_s[tid] = 0.f; best_s[tid] = ~0ULL;
        otZ_s[tid] = 0.f; otW_s[tid] = 0.f;
    }
    if (tid == 0) { ccnt = 0; dacc_s = 0.f; }
    __syncthreads();

    // ---- P1: stage top x (bf16) + exact |x4|^2 ----
    for (int idx = tid; idx < NT * 16; idx += 256) {
        int row = idx >> 4, k4 = (idx & 15) << 2;
        int l = t0 + row;
        float4 v = make_float4(0.f, 0.f, 0.f, 0.f);
        if (l < L) {
            v = *(const float4*)(xin4 + (size_t)l * 64 + k4);
            atomicAdd(&xn4_s[row], v.x * v.x + v.y * v.y + v.z * v.z + v.w * v.w);
        }
        u16x4 h; h[0] = f2bf(v.x); h[1] = f2bf(v.y); h[2] = f2bf(v.z); h[3] = f2bf(v.w);
        *(u16x4*)&x4_s[row * 72 + k4] = h;
    }
    __syncthreads();

    float runMin[2][4];
    #pragma unroll
    for (int mi = 0; mi < 2; ++mi)
        #pragma unroll
        for (int r = 0; r < 4; ++r) runMin[mi][r] = 3.4e38f;

    // ---- P2: TOP GEMM + band collect ----
    for (int cc = 0; cc < 2; ++cc) {
        const int colbase = cc * 256 + wid * 64;
        float n2v[4];
        #pragma unroll
        for (int ni = 0; ni < 4; ++ni) n2v[ni] = n2T[colbase + ni * 16 + l15];
        f32x4 acc[2][4] = {};
        #pragma unroll
        for (int ks = 0; ks < 2; ++ks) {
            s16x8 av[2], bv[4];
            #pragma unroll
            for (int mi = 0; mi < 2; ++mi)
                av[mi] = *(const s16x8*)&x4_s[(mi * 16 + l15) * 72 + ks * 32 + l4 * 8];
            #pragma unroll
            for (int ni = 0; ni < 4; ++ni)
                bv[ni] = *(const s16x8*)&ebT[(size_t)(colbase + ni * 16 + l15) * 64 + ks * 32 + l4 * 8];
            #pragma unroll
            for (int mi = 0; mi < 2; ++mi)
                #pragma unroll
                for (int ni = 0; ni < 4; ++ni)
                    acc[mi][ni] = __builtin_amdgcn_mfma_f32_16x16x32_bf16(
                        av[mi], bv[ni], acc[mi][ni], 0, 0, 0);
        }
        #pragma unroll
        for (int mi = 0; mi < 2; ++mi) {
            #pragma unroll
            for (int r = 0; r < 4; ++r) {
                const int row = mi * 16 + l4 * 4 + r;
                float dv[4];
                #pragma unroll
                for (int ni = 0; ni < 4; ++ni)
                    dv[ni] = n2v[ni] - 2.f * acc[mi][ni][r];
                float mnW = fminf(fminf(dv[0], dv[1]), fminf(dv[2], dv[3]));
                #pragma unroll
                for (int s = 1; s <= 8; s <<= 1)
                    mnW = fminf(mnW, __shfl_xor(mnW, s, 64));
                runMin[mi][r] = fminf(runMin[mi][r], mnW);
                const float thr = runMin[mi][r] + BAND;
                if (t0 + row < L) {
                    #pragma unroll
                    for (int ni = 0; ni < 4; ++ni) {
                        if (dv[ni] <= thr) {
                            int pos = atomicAdd(&ccnt, 1);
                            if (pos < CCAP) {
                                clist[pos] = ((unsigned)row << 16) |
                                             (unsigned)(colbase + ni * 16 + l15);
                                clv[pos] = dv[ni];
                            }
                        }
                    }
                }
            }
        }
    }
    #pragma unroll
    for (int mi = 0; mi < 2; ++mi)
        #pragma unroll
        for (int r = 0; r < 4; ++r)
            if (l15 == 0) wmin_s[wid][mi * 16 + l4 * 4 + r] = runMin[mi][r];
    __syncthreads();
    if (tid < NT)
        rowMinG[tid] = fminf(fminf(wmin_s[0][tid], wmin_s[1][tid]),
                             fminf(wmin_s[2][tid], wmin_s[3][tid]));
    __syncthreads();

    // ---- P3: TOP exact rescore (16-lane groups) ----
    {
        const int ncand = min(ccnt, CCAP);
        const int g = tid >> 4, li = tid & 15;
        for (int e = g; e < ncand; e += 16) {
            unsigned ent = clist[e];
            int row = ent >> 16, col = ent & 0xFFFF;
            if (clv[e] > rowMinG[row] + BAND) continue;
            int l = t0 + row;
            float4 xv = *(const float4*)(xin4 + (size_t)l * 64 + li * 4);
            float4 ev = *(const float4*)(cbT_T + (size_t)col * 64 + li * 4);
            float prod = xv.x * ev.x + xv.y * ev.y + xv.z * ev.z + xv.w * ev.w;
            #pragma unroll
            for (int s = 1; s <= 8; s <<= 1) prod += __shfl_xor(prod, s, 64);
            if (li == 0) {
                float dvE = n2T[col] - 2.f * prod;
                unsigned u = __float_as_uint(dvE);
                u = (u & 0x80000000u) ? ~u : (u | 0x80000000u);
                atomicMin(&best_s[row], ((unsigned long long)u << 32) | (unsigned)col);
            }
        }
    }
    __syncthreads();

    // ---- P4: TOP gather -> q4f + xL_s[64..127] + q4 norms + top diff ----
    {
        const int g = tid >> 4, li = tid & 15;
        for (int rr = g; rr < NT; rr += 16) {
            int l = t0 + rr;
            unsigned long long key = best_s[rr];
            float4 ev = make_float4(0.f, 0.f, 0.f, 0.f);
            float dvE = 0.f;
            if (l < L) {
                unsigned col = (unsigned)(key & 0xFFFFFFFFull);
                unsigned u = (unsigned)(key >> 32);
                u = (u & 0x80000000u) ? (u & 0x7FFFFFFFu) : ~u;
                dvE = __uint_as_float(u);
                ev = *(const float4*)(cbT_T + (size_t)col * 64 + li * 4);
            }
            *(float4*)&q4f[rr * 64 + li * 4] = ev;
            u16x4 h; h[0] = f2bf(ev.x); h[1] = f2bf(ev.y); h[2] = f2bf(ev.z); h[3] = f2bf(ev.w);
            *(u16x4*)&xL_s[rr * 136 + 64 + li * 4] = h;
            float qs = ev.x * ev.x + ev.y * ev.y + ev.z * ev.z + ev.w * ev.w;
            #pragma unroll
            for (int s = 1; s <= 8; s <<= 1) qs += __shfl_xor(qs, s, 64);
            if (li == 0) {
                xnq_s[rr] = qs;
                if (addTop && l < L)
                    atomicAdd(&dacc_s, (dvE + xn4_s[rr]) * (1.f / (L * 64.f)));
            }
        }
    }
    __syncthreads();

    // ---- P5: reset + stage level x (input j) ----
    if (tid < NT) best_s[tid] = ~0ULL;
    if (tid == 0) ccnt = 0;
    for (int idx = tid; idx < NT * 16; idx += 256) {
        int row = idx >> 4, k4 = (idx & 15) << 2;
        int l = t0 + row;
        float4 v = make_float4(0.f, 0.f, 0.f, 0.f);
        if (l < L) {
            v = *(const float4*)(xinj + (size_t)l * 64 + k4);
            atomicAdd(&xnL_s[row], v.x * v.x + v.y * v.y + v.z * v.z + v.w * v.w);
        }
        u16x4 h; h[0] = f2bf(v.x); h[1] = f2bf(v.y); h[2] = f2bf(v.z); h[3] = f2bf(v.w);
        *(u16x4*)&xL_s[row * 136 + k4] = h;
    }
    __syncthreads();

    // ---- P6: LEVEL GEMM + band collect + OT ----
    #pragma unroll
    for (int mi = 0; mi < 2; ++mi)
        #pragma unroll
        for (int r = 0; r < 4; ++r) runMin[mi][r] = 3.4e38f;

    for (int cc = 0; cc < 2; ++cc) {
        const int colbase = cc * 256 + wid * 64;
        float n2v[4], iv[4];
        #pragma unroll
        for (int ni = 0; ni < 4; ++ni) {
            n2v[ni] = n2L[colbase + ni * 16 + l15];
            if (OT) iv[ni] = ive[colbase + ni * 16 + l15];
        }
        f32x4 acc[2][4] = {};
        #pragma unroll
        for (int ks = 0; ks < 4; ++ks) {
            s16x8 av[2], bv[4];
            #pragma unroll
            for (int mi = 0; mi < 2; ++mi)
                av[mi] = *(const s16x8*)&xL_s[(mi * 16 + l15) * 136 + ks * 32 + l4 * 8];
            #pragma unroll
            for (int ni = 0; ni < 4; ++ni)
                bv[ni] = *(const s16x8*)&ebL[(size_t)(colbase + ni * 16 + l15) * 128 + ks * 32 + l4 * 8];
            #pragma unroll
            for (int mi = 0; mi < 2; ++mi)
                #pragma unroll
                for (int ni = 0; ni < 4; ++ni)
                    acc[mi][ni] = __builtin_amdgcn_mfma_f32_16x16x32_bf16(
                        av[mi], bv[ni], acc[mi][ni], 0, 0, 0);
        }
        #pragma unroll
        for (int mi = 0; mi < 2; ++mi) {
            #pragma unroll
            for (int r = 0; r < 4; ++r) {
                const int row = mi * 16 + l4 * 4 + r;
                float dv[4];
                #pragma unroll
                for (int ni = 0; ni < 4; ++ni)
                    dv[ni] = n2v[ni] - 2.f * acc[mi][ni][r];
                float mnW = fminf(fminf(dv[0], dv[1]), fminf(dv[2], dv[3]));
                #pragma unroll
                for (int s = 1; s <= 8; s <<= 1)
                    mnW = fminf(mnW, __shfl_xor(mnW, s, 64));
                runMin[mi][r] = fminf(runMin[mi][r], mnW);
                const float thr = runMin[mi][r] + BAND;
                if (t0 + row < L) {
                    #pragma unroll
                    for (int ni = 0; ni < 4; ++ni) {
                        if (dv[ni] <= thr) {
                            int pos = atomicAdd(&ccnt, 1);
                            if (pos < CCAP) {
                                clist[pos] = ((unsigned)row << 16) |
                                             (unsigned)(colbase + ni * 16 + l15);
                                clv[pos] = dv[ni];
                            }
                        }
                    }
                }
                if (OT) {
                    float xn = xnL_s[row] + xnq_s[row];
                    float ivx = 1.f / (sqrtf(xn) + 1e-8f);
                    float zloc = 0.f, wloc = 0.f;
                    #pragma unroll
                    for (int ni = 0; ni < 4; ++ni) {
                        float s = acc[mi][ni][r];
                        float e = __expf(s * (1.f / 512.f));
                        zloc += e;
                        wloc += (1.f - s * ivx * iv[ni]) * e;
                    }
                    #pragma unroll
                    for (int s = 1; s <= 8; s <<= 1) {
                        zloc += __shfl_xor(zloc, s, 64);
                        wloc += __shfl_xor(wloc, s, 64);
                    }
                    if (l15 == 0) {
                        atomicAdd(&otZ_s[row], zloc);
                        atomicAdd(&otW_s[row], wloc);
                    }
                }
            }
        }
    }
    #pragma unroll
    for (int mi = 0; mi < 2; ++mi)
        #pragma unroll
        for (int r = 0; r < 4; ++r)
            if (l15 == 0) wmin_s[wid][mi * 16 + l4 * 4 + r] = runMin[mi][r];
    __syncthreads();
    if (tid < NT)
        rowMinG[tid] = fminf(fminf(wmin_s[0][tid], wmin_s[1][tid]),
                             fminf(wmin_s[2][tid], wmin_s[3][tid]));
    __syncthreads();

    // ---- P7: LEVEL exact rescore (16-lane groups, 8 dims/lane) ----
    {
        const int ncand = min(ccnt, CCAP);
        const int g = tid >> 4, li = tid & 15;
        for (int e = g; e < ncand; e += 16) {
            unsigned ent = clist[e];
            int row = ent >> 16, col = ent & 0xFFFF;
            if (clv[e] > rowMinG[row] + BAND) continue;
            int l = t0 + row;
            int k = li * 8;
            float4 xa, xb;
            if (li < 8) {
                xa = *(const float4*)(xinj + (size_t)l * 64 + k);
                xb = *(const float4*)(xinj + (size_t)l * 64 + k + 4);
            } else {
                xa = *(const float4*)&q4f[row * 64 + (k - 64)];
                xb = *(const float4*)&q4f[row * 64 + (k - 60)];
            }
            float4 ea = *(const float4*)(cbT_L + (size_t)col * 128 + k);
            float4 eb = *(const float4*)(cbT_L + (size_t)col * 128 + k + 4);
            float prod = xa.x * ea.x + xa.y * ea.y + xa.z * ea.z + xa.w * ea.w +
                         xb.x * eb.x + xb.y * eb.y + xb.z * eb.z + xb.w * eb.w;
            #pragma unroll
            for (int s = 1; s <= 8; s <<= 1) prod += __shfl_xor(prod, s, 64);
            if (li == 0) {
                float dvE = n2L[col] - 2.f * prod;
                unsigned u = __float_as_uint(dvE);
                u = (u & 0x80000000u) ? ~u : (u | 0x80000000u);
                atomicMin(&best_s[row], ((unsigned long long)u << 32) | (unsigned)col);
            }
        }
    }
    __syncthreads();

    // ---- P8: write quant/id/ot + diff ----
    {
        const int slot = 3 - j;
        const int g = tid >> 4, li = tid & 15;
        for (int rr = g; rr < NT; rr += 16) {
            int l = t0 + rr;
            if (l >= L) continue;
            unsigned long long key = best_s[rr];
            unsigned col = (unsigned)(key & 0xFFFFFFFFull);
            unsigned u = (unsigned)(key >> 32);
            u = (u & 0x80000000u) ? (u & 0x7FFFFFFFu) : ~u;
            float dvE = __uint_as_float(u);
            float4 ea = *(const float4*)(cbT_L + (size_t)col * 128 + li * 8);
            float4 eb = *(const float4*)(cbT_L + (size_t)col * 128 + li * 8 + 4);
            float* dst = out + (((size_t)slot * B + b) * L + l) * 128 + li * 8;
            *(float4*)dst = ea;
            *(float4*)(dst + 4) = eb;
            if (li == 0) {
                out[ID_OFF + ((size_t)slot * B + b) * L + l] = (float)col;
                if (OT) out[OT_OFF + (size_t)b * L + l] = otW_s[rr] / otZ_s[rr];
                atomicAdd(&dacc_s, (dvE + xnL_s[rr] + xnq_s[rr]) * (1.f / (L * 128.f)));
            }
        }
    }
    __syncthreads();
    if (tid == 0) atomicAdd(out + DIFF_OFF, dacc_s);
}

extern "C" void kernel_launch(void* const* d_in, const int* in_sizes, int n_in,
                              void* d_out, int out_size, void* d_ws, size_t ws_size,
                              hipStream_t stream) {
    const float* input  = (const float*)d_in[0];
    const float* cb_top = (const float*)d_in[1];
    const float* cb_lvl = (const float*)d_in[2];
    const int*   label  = (const int*)d_in[3];
    float* out = (float*)d_out;
    float* ws  = (float*)d_ws;

    hipMemsetAsync(out + DIFF_OFF, 0, sizeof(float), stream);

    precompute<<<600, 256, 0, stream>>>(cb_top, cb_lvl, ws);
    vq_all<<<dim3(NTILES, B, 4), 256, 0, stream>>>(input, label, ws, out);
}

// Round 6
// 311.640 us; speedup vs baseline: 1.1106x; 1.1106x over previous
//
#include <hip/hip_runtime.h>
#include <hip/hip_bf16.h>
#include <math.h>

#define B 128
#define L 196
#define K 512
#define NCLS 15
#define NT 32
#define NTILES 7

// d_out layout (floats)
#define DIFF_OFF 12845056
#define ID_OFF   12845057
#define OT_OFF   12945409

// ws layout (float indices)
#define WS_N2   0                    // 75*512 ([0..14]=top, 15+j*15+c = lvl)
#define WS_INVE 38400                // 15*512
#define WS_PERM 46080                // 128 ints (class-sorted sample order)
#define WS_LAB  46208                // 128 ints (label copy)
#define WS_CBT  46336                // fp32 transposed codebooks [col][d]
#define CBT_LVL 491520               // float offset of lvl mats inside CBT
#define WS_EBT_BYTES ((size_t)(46336 + 4423680) * 4)  // bf16 [col][k] codebooks
#define EBT_LVL_BYTES 983040         // byte offset of lvl mats inside EBT

#define BAND 1.0f
#define CCAP 512

typedef __attribute__((ext_vector_type(8))) short s16x8;
typedef __attribute__((ext_vector_type(4))) float f32x4;
typedef __attribute__((ext_vector_type(4))) unsigned short u16x4;

__device__ inline unsigned short f2bf(float f) {
    __hip_bfloat16 h = __float2bfloat16(f);
    return *reinterpret_cast<unsigned short*>(&h);
}

// ---------------------------------------------------------------------------
// sort_labels: stable counting-sort of samples by class -> perm (rank -> b),
// plus a label copy into ws.
// ---------------------------------------------------------------------------
__global__ void sort_labels(const int* __restrict__ label, int* __restrict__ perm,
                            int* __restrict__ lab) {
    __shared__ int ls[B];
    const int t = threadIdx.x;
    ls[t] = label[t];
    lab[t] = ls[t];
    __syncthreads();
    const int mine = ls[t];
    int r = 0;
    for (int i = 0; i < B; ++i) {
        int li = ls[i];
        r += (li < mine) || (li == mine && i < t);
    }
    perm[r] = t;
}

// ---------------------------------------------------------------------------
// precompute: cbT fp32 [col][d], EBT bf16 [col][k], exact col norms, inve.
// ---------------------------------------------------------------------------
__global__ __launch_bounds__(256) void precompute(
    const float* __restrict__ cb_top, const float* __restrict__ cb_lvl,
    float* __restrict__ ws)
{
    __shared__ float Ld[128][65];
    __shared__ float ps[64][4];
    const int m = blockIdx.x >> 3;
    const int c0 = (blockIdx.x & 7) * 64;
    const bool top = m < NCLS;
    const int D = top ? 64 : 128;
    const float* src = top ? cb_top + (size_t)m * 64 * K
                           : cb_lvl + (size_t)(m - NCLS) * 128 * K;
    float* cbT = ws + WS_CBT + (top ? (size_t)m * K * 64
                                    : (size_t)CBT_LVL + (size_t)(m - NCLS) * K * 128);
    unsigned short* ebt = (unsigned short*)((char*)ws + WS_EBT_BYTES +
        (top ? (size_t)m * K * 64 * 2
             : (size_t)EBT_LVL_BYTES + (size_t)(m - NCLS) * K * 128 * 2));
    const int tid = threadIdx.x;

    for (int e = tid; e < D * 64; e += 256) {
        int d = e >> 6, cc = e & 63;
        Ld[d][cc] = src[(size_t)d * K + c0 + cc];
    }
    __syncthreads();

    const int col = tid >> 2, q = tid & 3;
    const int seg = D >> 2;
    float ss = 0.f;
    for (int i = 0; i < seg; ++i) {
        int d = q * seg + i;
        float v = Ld[d][col];
        ss = fmaf(v, v, ss);
        cbT[(size_t)(c0 + col) * D + d] = v;
        ebt[(size_t)(c0 + col) * D + d] = f2bf(v);
    }
    ps[col][q] = ss;
    __syncthreads();
    if (tid < 64) {
        float n2 = (ps[tid][0] + ps[tid][1]) + (ps[tid][2] + ps[tid][3]);
        ws[WS_N2 + (size_t)m * K + c0 + tid] = n2;
        if (m >= NCLS && m < 2 * NCLS)
            ws[WS_INVE + (size_t)(m - NCLS) * K + c0 + tid] = 1.f / (sqrtf(n2) + 1e-8f);
    }
}

// ---------------------------------------------------------------------------
// Fully fused VQ, class-locality scheduled. Per logical block (tile, ys, j):
// recompute top-VQ (q4 in LDS), then level-VQ. x rows live in LDS fp32.
// ---------------------------------------------------------------------------
__global__ __launch_bounds__(256, 4) void vq_all(
    const float* __restrict__ input, float* __restrict__ ws,
    float* __restrict__ out)
{
    __shared__ float uA[NT][68];                // x4f (P1-P3) then q4f (P4+)
    __shared__ float xLf[NT][68];               // input[j] fp32
    __shared__ unsigned short x4_s[NT * 72];    // top x bf16
    __shared__ unsigned short xL_s[NT * 136];   // level x bf16
    __shared__ float clv[CCAP];
    __shared__ unsigned int clist[CCAP];
    __shared__ float wmin_s[4][NT];
    __shared__ float rowMinG[NT];
    __shared__ unsigned long long best_s[NT];
    __shared__ float xn4_s[NT], xnL_s[NT], xnq_s[NT];
    __shared__ float otZ_s[NT], otW_s[NT];
    __shared__ float dacc_s;
    __shared__ int ccnt;

    const int tid = threadIdx.x;
    // ---- XCD-chunk swizzle + z-fastest logical decode (3584 = 8*448) ----
    const int hw = (int)blockIdx.x + 7 * (int)blockIdx.y + 896 * (int)blockIdx.z;
    const int logical = (hw & 7) * 448 + (hw >> 3);
    const int j = logical & 3;
    const int rest = logical >> 2;
    const int tile = rest % 7;
    const int ys = rest / 7;
    const int b = ((const int*)(ws + WS_PERM))[ys];
    const int cls = ((const int*)(ws + WS_LAB))[b];

    const bool OT = (j == 0);
    const bool addTop = (j == 3);
    const int t0 = tile * NT;
    const int wid = tid >> 6, lane = tid & 63, l15 = lane & 15, l4 = lane >> 4;

    const float* xin4 = input + ((size_t)(4 * B + b) * L) * 64;
    const float* xinj = input + ((size_t)(j * B + b) * L) * 64;
    const float* n2T = ws + WS_N2 + (size_t)cls * K;
    const float* n2L = ws + WS_N2 + (size_t)(NCLS + j * NCLS + cls) * K;
    const float* ive = ws + WS_INVE + (size_t)cls * K;
    const float* cbT_T = ws + WS_CBT + (size_t)cls * (K * 64);
    const float* cbT_L = ws + WS_CBT + CBT_LVL + (size_t)(j * NCLS + cls) * (K * 128);
    const unsigned short* ebT =
        (const unsigned short*)((const char*)ws + WS_EBT_BYTES) + (size_t)cls * (K * 64);
    const unsigned short* ebL =
        (const unsigned short*)((const char*)ws + WS_EBT_BYTES + EBT_LVL_BYTES) +
        (size_t)(j * NCLS + cls) * (K * 128);

    // ---- P0: init ----
    if (tid < NT) {
        xn4_s[tid] = 0.f; xnL_s[tid] = 0.f; best_s[tid] = ~0ULL;
        otZ_s[tid] = 0.f; otW_s[tid] = 0.f;
    }
    if (tid == 0) { ccnt = 0; dacc_s = 0.f; }
    __syncthreads();

    // ---- P1: stage top x (fp32 LDS + bf16) + prefetch level x fp32 ----
    for (int idx = tid; idx < NT * 16; idx += 256) {
        int row = idx >> 4, k4 = (idx & 15) << 2;
        int l = t0 + row;
        float4 v = make_float4(0.f, 0.f, 0.f, 0.f);
        if (l < L) {
            v = *(const float4*)(xin4 + (size_t)l * 64 + k4);
            atomicAdd(&xn4_s[row], v.x * v.x + v.y * v.y + v.z * v.z + v.w * v.w);
        }
        *(float4*)&uA[row][k4] = v;
        u16x4 h; h[0] = f2bf(v.x); h[1] = f2bf(v.y); h[2] = f2bf(v.z); h[3] = f2bf(v.w);
        *(u16x4*)&x4_s[row * 72 + k4] = h;
    }
    for (int idx = tid; idx < NT * 16; idx += 256) {
        int row = idx >> 4, k4 = (idx & 15) << 2;
        int l = t0 + row;
        float4 v = make_float4(0.f, 0.f, 0.f, 0.f);
        if (l < L) {
            v = *(const float4*)(xinj + (size_t)l * 64 + k4);
            atomicAdd(&xnL_s[row], v.x * v.x + v.y * v.y + v.z * v.z + v.w * v.w);
        }
        *(float4*)&xLf[row][k4] = v;
    }
    __syncthreads();

    float runMin[2][4];
    #pragma unroll
    for (int mi = 0; mi < 2; ++mi)
        #pragma unroll
        for (int r = 0; r < 4; ++r) runMin[mi][r] = 3.4e38f;

    // ---- P2: TOP GEMM + band collect ----
    for (int cc = 0; cc < 2; ++cc) {
        const int colbase = cc * 256 + wid * 64;
        float n2v[4];
        #pragma unroll
        for (int ni = 0; ni < 4; ++ni) n2v[ni] = n2T[colbase + ni * 16 + l15];
        f32x4 acc[2][4] = {};
        #pragma unroll
        for (int ks = 0; ks < 2; ++ks) {
            s16x8 av[2], bv[4];
            #pragma unroll
            for (int mi = 0; mi < 2; ++mi)
                av[mi] = *(const s16x8*)&x4_s[(mi * 16 + l15) * 72 + ks * 32 + l4 * 8];
            #pragma unroll
            for (int ni = 0; ni < 4; ++ni)
                bv[ni] = *(const s16x8*)&ebT[(size_t)(colbase + ni * 16 + l15) * 64 + ks * 32 + l4 * 8];
            #pragma unroll
            for (int mi = 0; mi < 2; ++mi)
                #pragma unroll
                for (int ni = 0; ni < 4; ++ni)
                    acc[mi][ni] = __builtin_amdgcn_mfma_f32_16x16x32_bf16(
                        av[mi], bv[ni], acc[mi][ni], 0, 0, 0);
        }
        #pragma unroll
        for (int mi = 0; mi < 2; ++mi) {
            #pragma unroll
            for (int r = 0; r < 4; ++r) {
                const int row = mi * 16 + l4 * 4 + r;
                float dv[4];
                #pragma unroll
                for (int ni = 0; ni < 4; ++ni)
                    dv[ni] = n2v[ni] - 2.f * acc[mi][ni][r];
                float mnW = fminf(fminf(dv[0], dv[1]), fminf(dv[2], dv[3]));
                #pragma unroll
                for (int s = 1; s <= 8; s <<= 1)
                    mnW = fminf(mnW, __shfl_xor(mnW, s, 64));
                runMin[mi][r] = fminf(runMin[mi][r], mnW);
                const float thr = runMin[mi][r] + BAND;
                if (t0 + row < L) {
                    #pragma unroll
                    for (int ni = 0; ni < 4; ++ni) {
                        if (dv[ni] <= thr) {
                            int pos = atomicAdd(&ccnt, 1);
                            if (pos < CCAP) {
                                clist[pos] = ((unsigned)row << 16) |
                                             (unsigned)(colbase + ni * 16 + l15);
                                clv[pos] = dv[ni];
                            }
                        }
                    }
                }
            }
        }
    }
    #pragma unroll
    for (int mi = 0; mi < 2; ++mi)
        #pragma unroll
        for (int r = 0; r < 4; ++r)
            if (l15 == 0) wmin_s[wid][mi * 16 + l4 * 4 + r] = runMin[mi][r];
    __syncthreads();
    if (tid < NT)
        rowMinG[tid] = fminf(fminf(wmin_s[0][tid], wmin_s[1][tid]),
                             fminf(wmin_s[2][tid], wmin_s[3][tid]));
    __syncthreads();

    // ---- P3: TOP exact rescore (16-lane groups, x from LDS) ----
    {
        const int ncand = min(ccnt, CCAP);
        const int g = tid >> 4, li = tid & 15;
        for (int e = g; e < ncand; e += 16) {
            unsigned ent = clist[e];
            int row = ent >> 16, col = ent & 0xFFFF;
            if (clv[e] > rowMinG[row] + BAND) continue;
            float4 xv = *(const float4*)&uA[row][li * 4];
            float4 ev = *(const float4*)(cbT_T + (size_t)col * 64 + li * 4);
            float prod = xv.x * ev.x + xv.y * ev.y + xv.z * ev.z + xv.w * ev.w;
            #pragma unroll
            for (int s = 1; s <= 8; s <<= 1) prod += __shfl_xor(prod, s, 64);
            if (li == 0) {
                float dvE = n2T[col] - 2.f * prod;
                unsigned u = __float_as_uint(dvE);
                u = (u & 0x80000000u) ? ~u : (u | 0x80000000u);
                atomicMin(&best_s[row], ((unsigned long long)u << 32) | (unsigned)col);
            }
        }
    }
    __syncthreads();

    // ---- P4: TOP winner gather -> q4f (overwrites x4f) + xL_s hi + diff ----
    {
        const int g = tid >> 4, li = tid & 15;
        #pragma unroll
        for (int rr0 = 0; rr0 < NT; rr0 += 16) {
            const int rr = rr0 + g;
            int l = t0 + rr;
            unsigned long long key = best_s[rr];
            float4 ev = make_float4(0.f, 0.f, 0.f, 0.f);
            float dvE = 0.f;
            if (l < L) {
                unsigned col = (unsigned)(key & 0xFFFFFFFFull);
                unsigned u = (unsigned)(key >> 32);
                u = (u & 0x80000000u) ? (u & 0x7FFFFFFFu) : ~u;
                dvE = __uint_as_float(u);
                ev = *(const float4*)(cbT_T + (size_t)col * 64 + li * 4);
            }
            float qs = ev.x * ev.x + ev.y * ev.y + ev.z * ev.z + ev.w * ev.w;
            #pragma unroll
            for (int s = 1; s <= 8; s <<= 1) qs += __shfl_xor(qs, s, 64);
            __syncthreads();                 // all prior reads of uA complete
            *(float4*)&uA[rr][li * 4] = ev;  // q4f
            u16x4 h; h[0] = f2bf(ev.x); h[1] = f2bf(ev.y); h[2] = f2bf(ev.z); h[3] = f2bf(ev.w);
            *(u16x4*)&xL_s[rr * 136 + 64 + li * 4] = h;
            if (li == 0) {
                xnq_s[rr] = qs;
                if (addTop && l < L)
                    atomicAdd(&dacc_s, (dvE + xn4_s[rr]) * (1.f / (L * 64.f)));
            }
        }
    }
    __syncthreads();

    // ---- P5: reset + convert level x fp32 -> bf16 LDS ----
    if (tid < NT) best_s[tid] = ~0ULL;
    if (tid == 0) ccnt = 0;
    for (int idx = tid; idx < NT * 16; idx += 256) {
        int row = idx >> 4, k4 = (idx & 15) << 2;
        float4 v = *(const float4*)&xLf[row][k4];
        u16x4 h; h[0] = f2bf(v.x); h[1] = f2bf(v.y); h[2] = f2bf(v.z); h[3] = f2bf(v.w);
        *(u16x4*)&xL_s[row * 136 + k4] = h;
    }
    __syncthreads();

    // ---- P6: LEVEL GEMM + band collect + OT ----
    #pragma unroll
    for (int mi = 0; mi < 2; ++mi)
        #pragma unroll
        for (int r = 0; r < 4; ++r) runMin[mi][r] = 3.4e38f;

    for (int cc = 0; cc < 2; ++cc) {
        const int colbase = cc * 256 + wid * 64;
        float n2v[4], iv[4];
        #pragma unroll
        for (int ni = 0; ni < 4; ++ni) {
            n2v[ni] = n2L[colbase + ni * 16 + l15];
            if (OT) iv[ni] = ive[colbase + ni * 16 + l15];
        }
        f32x4 acc[2][4] = {};
        #pragma unroll
        for (int ks = 0; ks < 4; ++ks) {
            s16x8 av[2], bv[4];
            #pragma unroll
            for (int mi = 0; mi < 2; ++mi)
                av[mi] = *(const s16x8*)&xL_s[(mi * 16 + l15) * 136 + ks * 32 + l4 * 8];
            #pragma unroll
            for (int ni = 0; ni < 4; ++ni)
                bv[ni] = *(const s16x8*)&ebL[(size_t)(colbase + ni * 16 + l15) * 128 + ks * 32 + l4 * 8];
            #pragma unroll
            for (int mi = 0; mi < 2; ++mi)
                #pragma unroll
                for (int ni = 0; ni < 4; ++ni)
                    acc[mi][ni] = __builtin_amdgcn_mfma_f32_16x16x32_bf16(
                        av[mi], bv[ni], acc[mi][ni], 0, 0, 0);
        }
        #pragma unroll
        for (int mi = 0; mi < 2; ++mi) {
            #pragma unroll
            for (int r = 0; r < 4; ++r) {
                const int row = mi * 16 + l4 * 4 + r;
                float dv[4];
                #pragma unroll
                for (int ni = 0; ni < 4; ++ni)
                    dv[ni] = n2v[ni] - 2.f * acc[mi][ni][r];
                float mnW = fminf(fminf(dv[0], dv[1]), fminf(dv[2], dv[3]));
                #pragma unroll
                for (int s = 1; s <= 8; s <<= 1)
                    mnW = fminf(mnW, __shfl_xor(mnW, s, 64));
                runMin[mi][r] = fminf(runMin[mi][r], mnW);
                const float thr = runMin[mi][r] + BAND;
                if (t0 + row < L) {
                    #pragma unroll
                    for (int ni = 0; ni < 4; ++ni) {
                        if (dv[ni] <= thr) {
                            int pos = atomicAdd(&ccnt, 1);
                            if (pos < CCAP) {
                                clist[pos] = ((unsigned)row << 16) |
                                             (unsigned)(colbase + ni * 16 + l15);
                                clv[pos] = dv[ni];
                            }
                        }
                    }
                }
                if (OT) {
                    float xn = xnL_s[row] + xnq_s[row];
                    float ivx = 1.f / (sqrtf(xn) + 1e-8f);
                    float zloc = 0.f, wloc = 0.f;
                    #pragma unroll
                    for (int ni = 0; ni < 4; ++ni) {
                        float s = acc[mi][ni][r];
                        float e = __expf(s * (1.f / 512.f));
                        zloc += e;
                        wloc += (1.f - s * ivx * iv[ni]) * e;
                    }
                    #pragma unroll
                    for (int s = 1; s <= 8; s <<= 1) {
                        zloc += __shfl_xor(zloc, s, 64);
                        wloc += __shfl_xor(wloc, s, 64);
                    }
                    if (l15 == 0) {
                        atomicAdd(&otZ_s[row], zloc);
                        atomicAdd(&otW_s[row], wloc);
                    }
                }
            }
        }
    }
    #pragma unroll
    for (int mi = 0; mi < 2; ++mi)
        #pragma unroll
        for (int r = 0; r < 4; ++r)
            if (l15 == 0) wmin_s[wid][mi * 16 + l4 * 4 + r] = runMin[mi][r];
    __syncthreads();
    if (tid < NT)
        rowMinG[tid] = fminf(fminf(wmin_s[0][tid], wmin_s[1][tid]),
                             fminf(wmin_s[2][tid], wmin_s[3][tid]));
    __syncthreads();

    // ---- P7: LEVEL exact rescore (x from LDS) ----
    {
        const int ncand = min(ccnt, CCAP);
        const int g = tid >> 4, li = tid & 15;
        for (int e = g; e < ncand; e += 16) {
            unsigned ent = clist[e];
            int row = ent >> 16, col = ent & 0xFFFF;
            if (clv[e] > rowMinG[row] + BAND) continue;
            float4 xa = *(const float4*)&xLf[row][li * 4];
            float4 xb = *(const float4*)&uA[row][li * 4];
            float4 ea = *(const float4*)(cbT_L + (size_t)col * 128 + li * 4);
            float4 eb = *(const float4*)(cbT_L + (size_t)col * 128 + 64 + li * 4);
            float prod = xa.x * ea.x + xa.y * ea.y + xa.z * ea.z + xa.w * ea.w +
                         xb.x * eb.x + xb.y * eb.y + xb.z * eb.z + xb.w * eb.w;
            #pragma unroll
            for (int s = 1; s <= 8; s <<= 1) prod += __shfl_xor(prod, s, 64);
            if (li == 0) {
                float dvE = n2L[col] - 2.f * prod;
                unsigned u = __float_as_uint(dvE);
                u = (u & 0x80000000u) ? ~u : (u | 0x80000000u);
                atomicMin(&best_s[row], ((unsigned long long)u << 32) | (unsigned)col);
            }
        }
    }
    __syncthreads();

    // ---- P8: write quant/id/ot + diff (contiguous-per-instruction stores) ----
    {
        const int slot = 3 - j;
        const int g = tid >> 4, li = tid & 15;
        for (int rr = g; rr < NT; rr += 16) {
            int l = t0 + rr;
            if (l >= L) continue;
            unsigned long long key = best_s[rr];
            unsigned col = (unsigned)(key & 0xFFFFFFFFull);
            unsigned u = (unsigned)(key >> 32);
            u = (u & 0x80000000u) ? (u & 0x7FFFFFFFu) : ~u;
            float dvE = __uint_as_float(u);
            float4 ea = *(const float4*)(cbT_L + (size_t)col * 128 + li * 4);
            float4 eb = *(const float4*)(cbT_L + (size_t)col * 128 + 64 + li * 4);
            float* dst = out + (((size_t)slot * B + b) * L + l) * 128;
            *(float4*)(dst + li * 4) = ea;
            *(float4*)(dst + 64 + li * 4) = eb;
            if (li == 0) {
                out[ID_OFF + ((size_t)slot * B + b) * L + l] = (float)col;
                if (OT) out[OT_OFF + (size_t)b * L + l] = otW_s[rr] / otZ_s[rr];
                atomicAdd(&dacc_s, (dvE + xnL_s[rr] + xnq_s[rr]) * (1.f / (L * 128.f)));
            }
        }
    }
    __syncthreads();
    if (tid == 0) atomicAdd(out + DIFF_OFF, dacc_s);
}

extern "C" void kernel_launch(void* const* d_in, const int* in_sizes, int n_in,
                              void* d_out, int out_size, void* d_ws, size_t ws_size,
                              hipStream_t stream) {
    const float* input  = (const float*)d_in[0];
    const float* cb_top = (const float*)d_in[1];
    const float* cb_lvl = (const float*)d_in[2];
    const int*   label  = (const int*)d_in[3];
    float* out = (float*)d_out;
    float* ws  = (float*)d_ws;

    hipMemsetAsync(out + DIFF_OFF, 0, sizeof(float), stream);

    sort_labels<<<1, B, 0, stream>>>(label, (int*)(ws + WS_PERM), (int*)(ws + WS_LAB));
    precompute<<<600, 256, 0, stream>>>(cb_top, cb_lvl, ws);
    vq_all<<<dim3(NTILES, B, 4), 256, 0, stream>>>(input, ws, out);
}

// Round 7
// 287.531 us; speedup vs baseline: 1.2037x; 1.0838x over previous
//
#include <hip/hip_runtime.h>
#include <hip/hip_bf16.h>
#include <math.h>

#define B 128
#define L 196
#define K 512
#define NCLS 15
#define NT 32
#define CCT 128
#define CCL 256

// d_out layout (floats)
#define DIFF_OFF 12845056
#define ID_OFF   12845057
#define OT_OFF   12945409

// ws layout (float indices)
#define WS_N2   0                    // 75*512 ([0..14]=top, 15+j*15+c = lvl)
#define WS_INVE 38400                // 15*512
#define WS_PERM 46080                // 128 ints
#define WS_LAB  46208                // 128 ints
#define WS_CBT  46336                // fp32 transposed codebooks [col][d]
#define CBT_LVL 491520               // float offset of lvl mats inside CBT
#define WS_EBT_BYTES ((size_t)(46336 + 4423680) * 4)  // bf16 [col][k]
#define EBT_LVL_BYTES 983040         // byte offset of lvl mats inside EBT

#define BAND 1.0f

typedef __attribute__((ext_vector_type(8))) short s16x8;
typedef __attribute__((ext_vector_type(4))) float f32x4;
typedef __attribute__((ext_vector_type(4))) unsigned short u16x4;

__device__ inline unsigned short f2bf(float f) {
    __hip_bfloat16 h = __float2bfloat16(f);
    return *reinterpret_cast<unsigned short*>(&h);
}

// ---------------------------------------------------------------------------
// sort_labels: stable counting-sort rank -> perm, plus label copy.
// ---------------------------------------------------------------------------
__global__ void sort_labels(const int* __restrict__ label, int* __restrict__ perm,
                            int* __restrict__ lab) {
    __shared__ int ls[B];
    const int t = threadIdx.x;
    ls[t] = label[t];
    lab[t] = ls[t];
    __syncthreads();
    const int mine = ls[t];
    int r = 0;
    for (int i = 0; i < B; ++i) {
        int li = ls[i];
        r += (li < mine) || (li == mine && i < t);
    }
    perm[r] = t;
}

// ---------------------------------------------------------------------------
// precompute (float4 IO): cbT fp32 [col][d], EBT bf16 [col][k], col norms.
// ---------------------------------------------------------------------------
__global__ __launch_bounds__(256) void precompute(
    const float* __restrict__ cb_top, const float* __restrict__ cb_lvl,
    float* __restrict__ ws)
{
    __shared__ float Ld[128][68];
    __shared__ float ps[64][4];
    const int m = blockIdx.x >> 3;
    const int c0 = (blockIdx.x & 7) * 64;
    const bool top = m < NCLS;
    const int D = top ? 64 : 128;
    const float* src = top ? cb_top + (size_t)m * 64 * K
                           : cb_lvl + (size_t)(m - NCLS) * 128 * K;
    float* cbT = ws + WS_CBT + (top ? (size_t)m * K * 64
                                    : (size_t)CBT_LVL + (size_t)(m - NCLS) * K * 128);
    unsigned short* ebt = (unsigned short*)((char*)ws + WS_EBT_BYTES +
        (top ? (size_t)m * K * 64 * 2
             : (size_t)EBT_LVL_BYTES + (size_t)(m - NCLS) * K * 128 * 2));
    const int tid = threadIdx.x;

    const int nIt = (D * 16) / 256;
    for (int it = 0; it < nIt; ++it) {
        int idx = it * 256 + tid;
        int d = idx >> 4, c4 = (idx & 15) << 2;
        *(float4*)&Ld[d][c4] = *(const float4*)(src + (size_t)d * K + c0 + c4);
    }
    __syncthreads();

    const int col = tid >> 2, q = tid & 3;
    const int seg = D >> 2;
    float ss = 0.f;
    for (int i = 0; i < seg; i += 4) {
        int d = q * seg + i;
        float4 v = make_float4(Ld[d][col], Ld[d + 1][col], Ld[d + 2][col], Ld[d + 3][col]);
        ss = fmaf(v.x, v.x, ss); ss = fmaf(v.y, v.y, ss);
        ss = fmaf(v.z, v.z, ss); ss = fmaf(v.w, v.w, ss);
        *(float4*)(cbT + (size_t)(c0 + col) * D + d) = v;
        u16x4 h; h[0] = f2bf(v.x); h[1] = f2bf(v.y); h[2] = f2bf(v.z); h[3] = f2bf(v.w);
        *(u16x4*)(ebt + (size_t)(c0 + col) * D + d) = h;
    }
    ps[col][q] = ss;
    __syncthreads();
    if (tid < 64) {
        float n2 = (ps[tid][0] + ps[tid][1]) + (ps[tid][2] + ps[tid][3]);
        ws[WS_N2 + (size_t)m * K + c0 + tid] = n2;
        if (m >= NCLS && m < 2 * NCLS)
            ws[WS_INVE + (size_t)(m - NCLS) * K + c0 + tid] = 1.f / (sqrtf(n2) + 1e-8f);
    }
}

// ---------------------------------------------------------------------------
// One block per (tile, b): top-VQ once (8 waves on 512 cols), then all 4
// levels concurrently (wave-pair per level). 512 thr = 8 waves.
// ---------------------------------------------------------------------------
__global__ __launch_bounds__(512, 4) void vq_all(
    const float* __restrict__ input, float* __restrict__ ws,
    float* __restrict__ out)
{
    __shared__ unsigned short x4_s[NT * 72];
    __shared__ unsigned short xL_s[4][NT * 136];
    __shared__ float q4f[NT][68];
    __shared__ float clvT[CCT];
    __shared__ unsigned int clistT[CCT];
    __shared__ float clvL[4][CCL];
    __shared__ unsigned int clistL[4][CCL];
    __shared__ float wminT[8][NT];
    __shared__ float wminL[4][2][NT];
    __shared__ float rowMinT[NT];
    __shared__ float rowMinL[4][NT];
    __shared__ unsigned long long bestT[NT];
    __shared__ unsigned long long bestL[4][NT];
    __shared__ float xn4_s[NT], xnq_s[NT], xnL_s[4][NT];
    __shared__ float otZ_s[NT], otW_s[NT];
    __shared__ int ccntT, ccntL[4];
    __shared__ float dacc_s;

    const int tid = threadIdx.x;
    const int hw = (int)blockIdx.x + 7 * (int)blockIdx.y;   // 0..895
    const int logical = (hw & 7) * 112 + (hw >> 3);          // XCD-chunked
    const int tile = logical % 7;
    const int ys = logical / 7;
    const int b = ((const int*)(ws + WS_PERM))[ys];
    const int cls = ((const int*)(ws + WS_LAB))[b];
    const int t0 = tile * NT;

    const int wid = tid >> 6, lane = tid & 63, l15 = lane & 15, l4 = lane >> 4;
    const int g = tid >> 4, li = tid & 15;

    const float* xin4 = input + ((size_t)(4 * B + b) * L) * 64;
    const float* n2T = ws + WS_N2 + (size_t)cls * K;
    const float* ive = ws + WS_INVE + (size_t)cls * K;
    const float* cbT_T = ws + WS_CBT + (size_t)cls * (K * 64);
    const unsigned short* ebT =
        (const unsigned short*)((const char*)ws + WS_EBT_BYTES) + (size_t)cls * (K * 64);

    // ---- P0: init ----
    if (tid < NT) {
        bestT[tid] = ~0ULL;
        otZ_s[tid] = 0.f; otW_s[tid] = 0.f;
    }
    if (tid < 4 * NT) bestL[tid >> 5][tid & 31] = ~0ULL;
    if (tid == 0) { ccntT = 0; dacc_s = 0.f; }
    if (tid < 4) ccntL[tid] = 0;
    __syncthreads();

    // ---- P1: stage x (bf16 LDS) + norms via shfl (no atomics) ----
    {
        const int row = g;
        const int l = t0 + row;
        #pragma unroll
        for (int jj = 0; jj < 5; ++jj) {
            const float* src = input + ((size_t)(jj * B + b) * L) * 64;
            float4 v = make_float4(0.f, 0.f, 0.f, 0.f);
            if (l < L) v = *(const float4*)(src + (size_t)l * 64 + li * 4);
            float ss = v.x * v.x + v.y * v.y + v.z * v.z + v.w * v.w;
            #pragma unroll
            for (int s = 1; s <= 8; s <<= 1) ss += __shfl_xor(ss, s, 64);
            u16x4 h; h[0] = f2bf(v.x); h[1] = f2bf(v.y); h[2] = f2bf(v.z); h[3] = f2bf(v.w);
            if (jj < 4) {
                *(u16x4*)&xL_s[jj][row * 136 + li * 4] = h;
                if (li == 0) xnL_s[jj][row] = ss;
            } else {
                *(u16x4*)&x4_s[row * 72 + li * 4] = h;
                if (li == 0) xn4_s[row] = ss;
            }
        }
    }
    __syncthreads();

    // ---- P2a: TOP GEMM (8 waves x 64 cols) ----
    f32x4 accT[2][4] = {};
    float n2vT[4];
    {
        #pragma unroll
        for (int ni = 0; ni < 4; ++ni) n2vT[ni] = n2T[wid * 64 + ni * 16 + l15];
        #pragma unroll
        for (int ks = 0; ks < 2; ++ks) {
            s16x8 av[2], bv[4];
            #pragma unroll
            for (int mi = 0; mi < 2; ++mi)
                av[mi] = *(const s16x8*)&x4_s[(mi * 16 + l15) * 72 + ks * 32 + l4 * 8];
            #pragma unroll
            for (int ni = 0; ni < 4; ++ni)
                bv[ni] = *(const s16x8*)&ebT[(size_t)(wid * 64 + ni * 16 + l15) * 64 + ks * 32 + l4 * 8];
            #pragma unroll
            for (int mi = 0; mi < 2; ++mi)
                #pragma unroll
                for (int ni = 0; ni < 4; ++ni)
                    accT[mi][ni] = __builtin_amdgcn_mfma_f32_16x16x32_bf16(
                        av[mi], bv[ni], accT[mi][ni], 0, 0, 0);
        }
        #pragma unroll
        for (int mi = 0; mi < 2; ++mi) {
            #pragma unroll
            for (int r = 0; r < 4; ++r) {
                const int row = mi * 16 + l4 * 4 + r;
                float mnW = 3.4e38f;
                #pragma unroll
                for (int ni = 0; ni < 4; ++ni)
                    mnW = fminf(mnW, n2vT[ni] - 2.f * accT[mi][ni][r]);
                #pragma unroll
                for (int s = 1; s <= 8; s <<= 1)
                    mnW = fminf(mnW, __shfl_xor(mnW, s, 64));
                if (l15 == 0) wminT[wid][row] = mnW;
            }
        }
    }
    __syncthreads();
    if (tid < NT) {
        float mn = wminT[0][tid];
        #pragma unroll
        for (int w = 1; w < 8; ++w) mn = fminf(mn, wminT[w][tid]);
        rowMinT[tid] = mn;
    }
    __syncthreads();

    // ---- P2b: TOP collect vs GLOBAL min ----
    #pragma unroll
    for (int mi = 0; mi < 2; ++mi) {
        #pragma unroll
        for (int r = 0; r < 4; ++r) {
            const int row = mi * 16 + l4 * 4 + r;
            if (t0 + row >= L) continue;
            const float thr = rowMinT[row] + BAND;
            #pragma unroll
            for (int ni = 0; ni < 4; ++ni) {
                float dv = n2vT[ni] - 2.f * accT[mi][ni][r];
                if (dv <= thr) {
                    int pos = atomicAdd(&ccntT, 1);
                    if (pos < CCT) {
                        clistT[pos] = ((unsigned)row << 16) | (unsigned)(wid * 64 + ni * 16 + l15);
                        clvT[pos] = dv;
                    }
                }
            }
        }
    }
    __syncthreads();

    // ---- P3: TOP exact rescore (32 groups of 16) ----
    {
        const int n = min(ccntT, CCT);
        for (int e = g; e < n; e += 32) {
            unsigned ent = clistT[e];
            int row = ent >> 16, col = ent & 0xFFFF;
            int l = t0 + row;
            float4 xv = *(const float4*)(xin4 + (size_t)l * 64 + li * 4);
            float4 ev = *(const float4*)(cbT_T + (size_t)col * 64 + li * 4);
            float prod = xv.x * ev.x + xv.y * ev.y + xv.z * ev.z + xv.w * ev.w;
            #pragma unroll
            for (int s = 1; s <= 8; s <<= 1) prod += __shfl_xor(prod, s, 64);
            if (li == 0) {
                float dvE = n2T[col] - 2.f * prod;
                unsigned u = __float_as_uint(dvE);
                u = (u & 0x80000000u) ? ~u : (u | 0x80000000u);
                atomicMin(&bestT[row], ((unsigned long long)u << 32) | (unsigned)col);
            }
        }
    }
    __syncthreads();

    // ---- P4: TOP gather -> q4f + xL hi halves + xnq + top diff ----
    {
        const int row = g;
        const int l = t0 + row;
        unsigned long long key = bestT[row];
        float4 ev = make_float4(0.f, 0.f, 0.f, 0.f);
        float dvE = 0.f;
        if (l < L) {
            unsigned col = (unsigned)(key & 0xFFFFFFFFull);
            unsigned u = (unsigned)(key >> 32);
            u = (u & 0x80000000u) ? (u & 0x7FFFFFFFu) : ~u;
            dvE = __uint_as_float(u);
            ev = *(const float4*)(cbT_T + (size_t)col * 64 + li * 4);
        }
        *(float4*)&q4f[row][li * 4] = ev;
        u16x4 h; h[0] = f2bf(ev.x); h[1] = f2bf(ev.y); h[2] = f2bf(ev.z); h[3] = f2bf(ev.w);
        #pragma unroll
        for (int jj = 0; jj < 4; ++jj)
            *(u16x4*)&xL_s[jj][row * 136 + 64 + li * 4] = h;
        float qs = ev.x * ev.x + ev.y * ev.y + ev.z * ev.z + ev.w * ev.w;
        #pragma unroll
        for (int s = 1; s <= 8; s <<= 1) qs += __shfl_xor(qs, s, 64);
        if (li == 0) {
            xnq_s[row] = qs;
            if (l < L) atomicAdd(&dacc_s, (dvE + xn4_s[row]) * (1.f / (L * 64.f)));
        }
    }
    __syncthreads();

    // ---- P5: LEVEL GEMMs, all 4 levels concurrently (wave pair per level) ----
    {
        const int j = wid & 3, h = wid >> 2;
        const bool OT = (j == 0);
        const float* n2L = ws + WS_N2 + (size_t)(NCLS + j * NCLS + cls) * K;
        const unsigned short* ebL =
            (const unsigned short*)((const char*)ws + WS_EBT_BYTES + EBT_LVL_BYTES) +
            (size_t)(j * NCLS + cls) * (K * 128);
        const unsigned short* xj = xL_s[j];

        float runMin[2][4];
        float zS[2][4], wS[2][4];
        #pragma unroll
        for (int mi = 0; mi < 2; ++mi)
            #pragma unroll
            for (int r = 0; r < 4; ++r) {
                runMin[mi][r] = 3.4e38f;
                zS[mi][r] = 0.f; wS[mi][r] = 0.f;
            }

        for (int cc = 0; cc < 4; ++cc) {
            const int colbase = h * 256 + cc * 64;
            float n2v[4], iv[4];
            #pragma unroll
            for (int ni = 0; ni < 4; ++ni) {
                n2v[ni] = n2L[colbase + ni * 16 + l15];
                if (OT) iv[ni] = ive[colbase + ni * 16 + l15];
            }
            f32x4 acc[2][4] = {};
            #pragma unroll
            for (int ks = 0; ks < 4; ++ks) {
                s16x8 av[2], bv[4];
                #pragma unroll
                for (int mi = 0; mi < 2; ++mi)
                    av[mi] = *(const s16x8*)&xj[(mi * 16 + l15) * 136 + ks * 32 + l4 * 8];
                #pragma unroll
                for (int ni = 0; ni < 4; ++ni)
                    bv[ni] = *(const s16x8*)&ebL[(size_t)(colbase + ni * 16 + l15) * 128 + ks * 32 + l4 * 8];
                #pragma unroll
                for (int mi = 0; mi < 2; ++mi)
                    #pragma unroll
                    for (int ni = 0; ni < 4; ++ni)
                        acc[mi][ni] = __builtin_amdgcn_mfma_f32_16x16x32_bf16(
                            av[mi], bv[ni], acc[mi][ni], 0, 0, 0);
            }
            #pragma unroll
            for (int mi = 0; mi < 2; ++mi) {
                #pragma unroll
                for (int r = 0; r < 4; ++r) {
                    const int row = mi * 16 + l4 * 4 + r;
                    float dv[4];
                    #pragma unroll
                    for (int ni = 0; ni < 4; ++ni)
                        dv[ni] = n2v[ni] - 2.f * acc[mi][ni][r];
                    float mnW = fminf(fminf(dv[0], dv[1]), fminf(dv[2], dv[3]));
                    #pragma unroll
                    for (int s = 1; s <= 8; s <<= 1)
                        mnW = fminf(mnW, __shfl_xor(mnW, s, 64));
                    runMin[mi][r] = fminf(runMin[mi][r], mnW);
                    const float thr = runMin[mi][r] + BAND;
                    if (t0 + row < L) {
                        #pragma unroll
                        for (int ni = 0; ni < 4; ++ni) {
                            if (dv[ni] <= thr) {
                                int pos = atomicAdd(&ccntL[j], 1);
                                if (pos < CCL) {
                                    clistL[j][pos] = ((unsigned)row << 16) |
                                                     (unsigned)(colbase + ni * 16 + l15);
                                    clvL[j][pos] = dv[ni];
                                }
                            }
                        }
                    }
                    if (OT) {
                        #pragma unroll
                        for (int ni = 0; ni < 4; ++ni) {
                            float s = acc[mi][ni][r];
                            float e = __expf(s * (1.f / 512.f));
                            zS[mi][r] += e;
                            float xn = xnL_s[0][row] + xnq_s[row];
                            float ivx = 1.f / (sqrtf(xn) + 1e-8f);
                            wS[mi][r] += (1.f - s * ivx * iv[ni]) * e;
                        }
                    }
                }
            }
        }
        #pragma unroll
        for (int mi = 0; mi < 2; ++mi)
            #pragma unroll
            for (int r = 0; r < 4; ++r) {
                const int row = mi * 16 + l4 * 4 + r;
                if (l15 == 0) wminL[j][h][row] = runMin[mi][r];
                if (OT) {
                    float z = zS[mi][r], w = wS[mi][r];
                    #pragma unroll
                    for (int s = 1; s <= 8; s <<= 1) {
                        z += __shfl_xor(z, s, 64);
                        w += __shfl_xor(w, s, 64);
                    }
                    if (l15 == 0) {
                        atomicAdd(&otZ_s[row], z);
                        atomicAdd(&otW_s[row], w);
                    }
                }
            }
    }
    __syncthreads();
    if (tid < 4 * NT) {
        int jj = tid >> 5, row = tid & 31;
        rowMinL[jj][row] = fminf(wminL[jj][0][row], wminL[jj][1][row]);
    }
    __syncthreads();

    // ---- P6: LEVEL exact rescore (x from global L2, q4 from LDS) ----
    for (int jj = 0; jj < 4; ++jj) {
        const int n = min(ccntL[jj], CCL);
        const float* xinj = input + ((size_t)(jj * B + b) * L) * 64;
        const float* cbT_Lj = ws + WS_CBT + CBT_LVL + (size_t)(jj * NCLS + cls) * (K * 128);
        const float* n2L = ws + WS_N2 + (size_t)(NCLS + jj * NCLS + cls) * K;
        for (int e = g; e < n; e += 32) {
            unsigned ent = clistL[jj][e];
            int row = ent >> 16, col = ent & 0xFFFF;
            if (clvL[jj][e] > rowMinL[jj][row] + BAND) continue;
            int l = t0 + row;
            float4 xa, xb;
            if (li < 8) {
                xa = *(const float4*)(xinj + (size_t)l * 64 + li * 8);
                xb = *(const float4*)(xinj + (size_t)l * 64 + li * 8 + 4);
            } else {
                xa = *(const float4*)&q4f[row][(li - 8) * 8];
                xb = *(const float4*)&q4f[row][(li - 8) * 8 + 4];
            }
            float4 ea = *(const float4*)(cbT_Lj + (size_t)col * 128 + li * 8);
            float4 eb = *(const float4*)(cbT_Lj + (size_t)col * 128 + li * 8 + 4);
            float prod = xa.x * ea.x + xa.y * ea.y + xa.z * ea.z + xa.w * ea.w +
                         xb.x * eb.x + xb.y * eb.y + xb.z * eb.z + xb.w * eb.w;
            #pragma unroll
            for (int s = 1; s <= 8; s <<= 1) prod += __shfl_xor(prod, s, 64);
            if (li == 0) {
                float dvE = n2L[col] - 2.f * prod;
                unsigned u = __float_as_uint(dvE);
                u = (u & 0x80000000u) ? ~u : (u | 0x80000000u);
                atomicMin(&bestL[jj][row], ((unsigned long long)u << 32) | (unsigned)col);
            }
        }
    }
    __syncthreads();

    // ---- P7: write quant/id/ot + level diff ----
    #pragma unroll
    for (int it = 0; it < 4; ++it) {
        int p = it * 32 + g;              // 128 (row, level) pairs
        int jj = p & 3, row = p >> 2;
        int l = t0 + row;
        if (l >= L) continue;
        const float* cbT_Lj = ws + WS_CBT + CBT_LVL + (size_t)(jj * NCLS + cls) * (K * 128);
        unsigned long long key = bestL[jj][row];
        unsigned col = (unsigned)(key & 0xFFFFFFFFull);
        unsigned u = (unsigned)(key >> 32);
        u = (u & 0x80000000u) ? (u & 0x7FFFFFFFu) : ~u;
        float dvE = __uint_as_float(u);
        float4 ea = *(const float4*)(cbT_Lj + (size_t)col * 128 + li * 8);
        float4 eb = *(const float4*)(cbT_Lj + (size_t)col * 128 + li * 8 + 4);
        const int slot = 3 - jj;
        float* dst = out + (((size_t)slot * B + b) * L + l) * 128 + li * 8;
        *(float4*)dst = ea;
        *(float4*)(dst + 4) = eb;
        if (li == 0) {
            out[ID_OFF + ((size_t)slot * B + b) * L + l] = (float)col;
            if (jj == 0) out[OT_OFF + (size_t)b * L + l] = otW_s[row] / otZ_s[row];
            atomicAdd(&dacc_s, (dvE + xnL_s[jj][row] + xnq_s[row]) * (1.f / (L * 128.f)));
        }
    }
    __syncthreads();
    if (tid == 0) atomicAdd(out + DIFF_OFF, dacc_s);
}

extern "C" void kernel_launch(void* const* d_in, const int* in_sizes, int n_in,
                              void* d_out, int out_size, void* d_ws, size_t ws_size,
                              hipStream_t stream) {
    const float* input  = (const float*)d_in[0];
    const float* cb_top = (const float*)d_in[1];
    const float* cb_lvl = (const float*)d_in[2];
    const int*   label  = (const int*)d_in[3];
    float* out = (float*)d_out;
    float* ws  = (float*)d_ws;

    hipMemsetAsync(out + DIFF_OFF, 0, sizeof(float), stream);

    sort_labels<<<1, B, 0, stream>>>(label, (int*)(ws + WS_PERM), (int*)(ws + WS_LAB));
    precompute<<<600, 256, 0, stream>>>(cb_top, cb_lvl, ws);
    vq_all<<<dim3(7, B), 512, 0, stream>>>(input, ws, out);
}